// Round 8
// baseline (383.821 us; speedup 1.0000x reference)
//
#include <hip/hip_runtime.h>
#include <hip/hip_bf16.h>

#define NSEQ 4096
#define DHEAD 128
#define NB 4

typedef __attribute__((ext_vector_type(8))) short bf16x8;
typedef __attribute__((ext_vector_type(16))) float f32x16;
typedef __attribute__((ext_vector_type(4))) unsigned int u32x4;

// ws byte offsets
#define KF_S 0u
#define KF_G 4194304u
#define VF_S 8388608u
#define VF_G 12582912u
#define PBUF_OFF 16777216u   // f32 [zk=8][b=4][4096][128]  (64 MB)
#define LBUF_OFF 83886080u   // f32 [zk=8][b=4][4096]       (512 KB)

typedef __attribute__((address_space(3))) void lds_void;
typedef const __attribute__((address_space(1))) void g_void;
#define GLOAD(gp, lp) __builtin_amdgcn_global_load_lds((g_void*)(gp), (lds_void*)(lp), 16, 0, 0)

__device__ __forceinline__ unsigned cvtpk(float lo, float hi) {
  unsigned r;
  asm("v_cvt_pk_bf16_f32 %0, %1, %2" : "=v"(r) : "v"(lo), "v"(hi));
  return r;
}

// v_permlane32_swap_b32 vdst, vsrc : vdst.lanes[32:63] <-> vsrc.lanes[0:31]
__device__ __forceinline__ void plswap(unsigned& x, unsigned& y) {
#if defined(__has_builtin)
#if __has_builtin(__builtin_amdgcn_permlane32_swap)
  typedef unsigned u2 __attribute__((ext_vector_type(2)));
  u2 r = __builtin_amdgcn_permlane32_swap(x, y, false, false);
  x = r[0]; y = r[1];
#else
  asm("v_permlane32_swap_b32 %0, %1" : "+v"(x), "+v"(y));
#endif
#else
  asm("v_permlane32_swap_b32 %0, %1" : "+v"(x), "+v"(y));
#endif
}

// ---------- prep: fp32 -> bf16 fragment-major K frags + V^T frags ----------
__global__ __launch_bounds__(256) void prep4(const float* __restrict__ S,
                                             const float* __restrict__ G,
                                             unsigned short* __restrict__ ws) {
  const int t = blockIdx.x, b = blockIdx.y, tens = blockIdx.z;   // 32-row tile t
  const float* X = (tens ? G : S) + ((size_t)b * NSEQ + t * 32) * DHEAD;
  unsigned short* Kf = ws + ((tens ? KF_G : KF_S) >> 1) + (size_t)b * 524288 + (size_t)t * 4096;
  unsigned short* Vf = ws + ((tens ? VF_G : VF_S) >> 1) + (size_t)b * 524288 + (size_t)t * 4096;
  __shared__ unsigned short tl[32 * 132];
  const int tid = threadIdx.x;
  {
    const int c = tid >> 5, r = tid & 31;          // K frag c, kv-row r
    const float* xp = X + (size_t)r * DHEAD + c * 16;
    float4 v0 = *(const float4*)(xp);
    float4 v1 = *(const float4*)(xp + 4);
    float4 v2 = *(const float4*)(xp + 8);
    float4 v3 = *(const float4*)(xp + 12);
    unsigned w0 = cvtpk(v0.x, v0.y), w1 = cvtpk(v0.z, v0.w);
    unsigned w2 = cvtpk(v1.x, v1.y), w3 = cvtpk(v1.z, v1.w);
    unsigned w4 = cvtpk(v2.x, v2.y), w5 = cvtpk(v2.z, v2.w);
    unsigned w6 = cvtpk(v3.x, v3.y), w7 = cvtpk(v3.z, v3.w);
    u32x4 lo4 = {w0, w1, w2, w3}, hi4 = {w4, w5, w6, w7};
    *(u32x4*)(Kf + c * 512 + r * 8) = lo4;          // lane r   : d=16c+0..7
    *(u32x4*)(Kf + c * 512 + (r + 32) * 8) = hi4;   // lane r+32: d=16c+8..15
    unsigned* tp = (unsigned*)&tl[r * 132 + c * 16];
    tp[0] = w0; tp[1] = w1; tp[2] = w2; tp[3] = w3;
    tp[4] = w4; tp[5] = w5; tp[6] = w6; tp[7] = w7;
  }
  __syncthreads();
  {
    const int f = tid >> 5, dc = tid & 31;          // V frag f = c2*4+dblk
    const int c2 = f >> 2, dblk = f & 3;
    const int dcol = dblk * 32 + dc;
    unsigned a[4], bb[4];
    #pragma unroll
    for (int j2 = 0; j2 < 4; ++j2) {
      a[j2]  = (unsigned)tl[(16 * c2 + 2 * j2) * 132 + dcol] |
               ((unsigned)tl[(16 * c2 + 2 * j2 + 1) * 132 + dcol] << 16);
      bb[j2] = (unsigned)tl[(16 * c2 + 8 + 2 * j2) * 132 + dcol] |
               ((unsigned)tl[(16 * c2 + 9 + 2 * j2) * 132 + dcol] << 16);
    }
    *(u32x4*)(Vf + f * 512 + dc * 8) = *(u32x4*)a;          // lane dc   : kv=16c2+0..7
    *(u32x4*)(Vf + f * 512 + (dc + 32) * 8) = *(u32x4*)bb;  // lane dc+32: kv=16c2+8..15
  }
}

// ---------- main: 4 waves = q-subtiles; swapped QK^T, in-register P ----------
__global__ __launch_bounds__(256, 4)
void xattn4(const float* __restrict__ S, const float* __restrict__ G,
            const unsigned short* __restrict__ ws, float* __restrict__ pbuf,
            float* __restrict__ lbuf) {
  const int qks = blockIdx.x;                 // qblk*4 + ks
  const int qblk = qks >> 2, ks = qks & 3;
  const int b = blockIdx.y, z = blockIdx.z;   // z=0: Q=S,KV=G ; z=1: Q=G,KV=S
  const int tid = threadIdx.x, w = tid >> 6, l = tid & 63;
  const int hi = l >> 5, lo = l & 31;

  const float* Q = (z ? G : S) + (size_t)b * NSEQ * DHEAD;
  const unsigned short* Kf = ws + ((z ? KF_S : KF_G) >> 1) + (size_t)b * 524288;
  const unsigned short* Vf = ws + ((z ? VF_S : VF_G) >> 1) + (size_t)b * 524288;

  __shared__ __align__(16) char smem[16384];  // K dbuf 2 x 8KB

  const int q0w = qblk * 128 + w * 32;
  const float qsc = 0.08838834764831845f * 1.44269504088896341f; // 1/sqrt(D)*log2(e)

  // Q fragments (B-operand): lane l -> Q[q0w+lo][16c + hi*8 + j]
  bf16x8 qf[8];
  {
    const float* qs = Q + (size_t)(q0w + lo) * DHEAD + hi * 8;
    #pragma unroll
    for (int c = 0; c < 8; ++c) {
      float4 a = *(const float4*)(qs + c * 16);
      float4 bq = *(const float4*)(qs + c * 16 + 4);
      u32x4 u = {cvtpk(a.x * qsc, a.y * qsc), cvtpk(a.z * qsc, a.w * qsc),
                 cvtpk(bq.x * qsc, bq.y * qsc), cvtpk(bq.z * qsc, bq.w * qsc)};
      qf[c] = __builtin_bit_cast(bf16x8, u);
    }
  }

  f32x16 oac[4];
  #pragma unroll
  for (int d = 0; d < 4; ++d)
    #pragma unroll
    for (int r = 0; r < 16; ++r) oac[d][r] = 0.f;
  float lsum = 0.f;

  const int t0 = ks * 32;                     // 32 kv-tiles of 32 rows each
  const unsigned short* kg0 = Kf + (size_t)t0 * 4096 + (2 * w) * 512 + l * 8;
  char* klw = smem + (2 * w) * 1024;          // this wave's 2KB slice (uniform base)

  GLOAD(kg0, klw); GLOAD(kg0 + 512, klw + 1024);
  __syncthreads();

  for (int i = 0; i < 32; ++i) {
    const int par = i & 1;
    const char* kb = smem + par * 8192;

    // V fragments for tile i (L1/L2; shared across the 4 waves)
    const unsigned short* vt = Vf + (size_t)(t0 + i) * 4096 + l * 8;
    bf16x8 vfr[8];
    #pragma unroll
    for (int f = 0; f < 8; ++f) vfr[f] = *(const bf16x8*)(vt + f * 512);

    // swapped QK^T: sim = K x Q^T, two independent accumulation chains for ILP
    __builtin_amdgcn_s_setprio(1);
    f32x16 s0 = {}, s1 = {};
    #pragma unroll
    for (int c = 0; c < 4; ++c) {
      bf16x8 k0 = *(const bf16x8*)(kb + c * 1024 + l * 16);
      bf16x8 k1 = *(const bf16x8*)(kb + (4 + c) * 1024 + l * 16);
      s0 = __builtin_amdgcn_mfma_f32_32x32x16_bf16(k0, qf[c], s0, 0, 0, 0);
      s1 = __builtin_amdgcn_mfma_f32_32x32x16_bf16(k1, qf[4 + c], s1, 0, 0, 0);
    }
    __builtin_amdgcn_s_setprio(0);
    f32x16 sim = s0 + s1;

    // prefetch K(i+1) into other parity (in flight until end-of-iter barrier)
    if (i < 31) {
      const unsigned short* kg = Kf + (size_t)(t0 + i + 1) * 4096 + (2 * w) * 512 + l * 8;
      char* kl = smem + (par ^ 1) * 8192 + (2 * w) * 1024;
      GLOAD(kg, kl); GLOAD(kg + 512, kl + 1024);
    }

    // p = exp2(sim); lane-local partial of softmax denominator
    float p[16];
    #pragma unroll
    for (int r = 0; r < 16; ++r) p[r] = __builtin_amdgcn_exp2f(sim[r]);
    lsum += ((((p[0] + p[1]) + (p[2] + p[3])) + ((p[4] + p[5]) + (p[6] + p[7]))) +
             (((p[8] + p[9]) + (p[10] + p[11])) + ((p[12] + p[13]) + (p[14] + p[15]))));

    // pack to bf16 + permlane32_swap -> PV A-fragments (no LDS, no barrier)
    unsigned pa = cvtpk(p[0], p[1]),   pb = cvtpk(p[2], p[3]);
    unsigned pc = cvtpk(p[4], p[5]),   pd = cvtpk(p[6], p[7]);
    unsigned pe = cvtpk(p[8], p[9]),   pf = cvtpk(p[10], p[11]);
    unsigned pg = cvtpk(p[12], p[13]), ph = cvtpk(p[14], p[15]);
    plswap(pa, pc);   // pa -> w0, pc -> w2
    plswap(pb, pd);   // pb -> w1, pd -> w3
    plswap(pe, pg);   // pe -> w4, pg -> w6
    plswap(pf, ph);   // pf -> w5, ph -> w7
    u32x4 A0 = {pa, pb, pc, pd};
    u32x4 A1 = {pe, pf, pg, ph};
    bf16x8 pA0 = __builtin_bit_cast(bf16x8, A0);
    bf16x8 pA1 = __builtin_bit_cast(bf16x8, A1);

    // PV: O[q][d] += P·V  (4 independent d-block chains)
    __builtin_amdgcn_s_setprio(1);
    #pragma unroll
    for (int d = 0; d < 4; ++d) {
      oac[d] = __builtin_amdgcn_mfma_f32_32x32x16_bf16(pA0, vfr[d], oac[d], 0, 0, 0);
      oac[d] = __builtin_amdgcn_mfma_f32_32x32x16_bf16(pA1, vfr[4 + d], oac[d], 0, 0, 0);
    }
    __builtin_amdgcn_s_setprio(0);
    __syncthreads();  // drains vmcnt -> K(i+1) staged; parity reuse safe
  }

  // ---- epilogue: partial O and l to workspace (no atomics) ----
  float lpart = lsum + __shfl(lsum, l ^ 32, 64);
  const int zk = z * 4 + ks;
  if (hi == 0)
    lbuf[(size_t)zk * (NB * NSEQ) + (size_t)b * NSEQ + q0w + lo] = lpart;
  float* ob = pbuf + ((size_t)zk * NB + b) * (NSEQ * DHEAD);
  #pragma unroll
  for (int d = 0; d < 4; ++d)
    #pragma unroll
    for (int r = 0; r < 16; ++r) {
      int row = (r & 3) + 8 * (r >> 2) + 4 * hi;
      ob[(size_t)(q0w + row) * DHEAD + d * 32 + lo] = oac[d][r];
    }
}

// ---------- finalize: out = 0.5*(sum_ks O_p0/l0 + sum_ks O_p1/l1) ----------
__global__ __launch_bounds__(256) void fin4(const float* __restrict__ pbuf,
                                            const float* __restrict__ lbuf,
                                            float* __restrict__ out) {
  const int idx = blockIdx.x * 256 + threadIdx.x;   // float4 unit, 524288 total
  const int row = idx >> 5, c4 = (idx & 31) * 4;
  const size_t R = (size_t)NB * NSEQ * DHEAD;
  const size_t o = (size_t)row * DHEAD + c4;
  float4 a = {0.f, 0.f, 0.f, 0.f}, bb = {0.f, 0.f, 0.f, 0.f};
  float l0 = 0.f, l1 = 0.f;
  #pragma unroll
  for (int k = 0; k < 4; ++k) {
    float4 av = *(const float4*)(pbuf + (size_t)k * R + o);
    float4 bv = *(const float4*)(pbuf + (size_t)(4 + k) * R + o);
    a.x += av.x; a.y += av.y; a.z += av.z; a.w += av.w;
    bb.x += bv.x; bb.y += bv.y; bb.z += bv.z; bb.w += bv.w;
    l0 += lbuf[k * 16384 + row];
    l1 += lbuf[(4 + k) * 16384 + row];
  }
  float i0 = 0.5f / l0, i1 = 0.5f / l1;
  float4 r;
  r.x = a.x * i0 + bb.x * i1;
  r.y = a.y * i0 + bb.y * i1;
  r.z = a.z * i0 + bb.z * i1;
  r.w = a.w * i0 + bb.w * i1;
  *(float4*)(out + o) = r;
}

extern "C" void kernel_launch(void* const* d_in, const int* in_sizes, int n_in,
                              void* d_out, int out_size, void* d_ws, size_t ws_size,
                              hipStream_t stream) {
  const float* S = (const float*)d_in[0];
  const float* G = (const float*)d_in[1];
  unsigned short* ws = (unsigned short*)d_ws;
  float* pbuf = (float*)((char*)d_ws + PBUF_OFF);
  float* lbuf = (float*)((char*)d_ws + LBUF_OFF);
  float* outp = (float*)d_out;
  prep4<<<dim3(128, 4, 2), 256, 0, stream>>>(S, G, ws);
  xattn4<<<dim3(128, 4, 2), 256, 0, stream>>>(S, G, ws, pbuf, lbuf);
  fin4<<<2048, 256, 0, stream>>>(pbuf, lbuf, outp);
}